// Round 5
// baseline (27.827 us; speedup 1.0000x reference)
//
#include <hip/hip_runtime.h>
#include <math.h>

#define NCLS 1784
#define NF4 446            // 1784 / 4
#define NBATCH 16384
#define ROWS_PER_BLOCK 8   // 2 rows per wave, 4 waves
#define NBLOCKS (NBATCH / ROWS_PER_BLOCK)   // 2048
#define LOG2E 1.4426950408889634f

// 4 waves per block; each wave owns 2 rows (14 float4 loads in flight).
// Block writes ONE partial (ce+penalty over its 8 rows) to ws.
__global__ __launch_bounds__(256) void cevp_row_kernel(
        const float* __restrict__ logits,
        const int* __restrict__ targets,
        const float* __restrict__ P,
        float* __restrict__ ws) {
    const int wave = threadIdx.x >> 6;          // 0..3
    const int lane = threadIdx.x & 63;
    const int row0 = blockIdx.x * ROWS_PER_BLOCK + wave * 2;
    const int row1 = row0 + 1;

    // Hoisted scattered loads: latency overlaps the bulk row loads below.
    const int   tgt0 = targets[row0];
    const int   tgt1 = targets[row1];
    const float lt0  = logits[(size_t)row0 * NCLS + tgt0];
    const float lt1  = logits[(size_t)row1 * NCLS + tgt1];

    const float4* __restrict__ rp0 =
        reinterpret_cast<const float4*>(logits + (size_t)row0 * NCLS);
    const float4* __restrict__ rp1 =
        reinterpret_cast<const float4*>(logits + (size_t)row1 * NCLS);

    // Both rows into registers: 14 independent float4 loads per lane.
    float4 a[7], b[7];
    #pragma unroll
    for (int k = 0; k < 7; ++k) {
        const int idx = lane + 64 * k;
        if (idx < NF4) { a[k] = rp0[idx]; b[k] = rp1[idx]; }
        else {
            a[k] = make_float4(-INFINITY, -INFINITY, -INFINITY, -INFINITY);
            b[k] = a[k];
        }
    }

    // Per-lane max + compact argmax code (4k+j in 0..27) for both rows.
    float ma = -INFINITY, mb = -INFINITY;
    int ca = 0, cb = 0;
    #pragma unroll
    for (int k = 0; k < 7; ++k) {
        const float* fa = reinterpret_cast<const float*>(&a[k]);
        const float* fb = reinterpret_cast<const float*>(&b[k]);
        #pragma unroll
        for (int j = 0; j < 4; ++j) {
            const bool ga = fa[j] > ma;
            ca = ga ? (k * 4 + j) : ca;
            ma = ga ? fa[j]       : ma;
            const bool gb = fb[j] > mb;
            cb = gb ? (k * 4 + j) : cb;
            mb = gb ? fb[j]       : mb;
        }
    }
    // True column index: idx = 256*k + 4*lane + j.
    int ia = ((ca >> 2) << 8) + (lane << 2) + (ca & 3);
    int ib = ((cb >> 2) << 8) + (lane << 2) + (cb & 3);

    // Wave-wide argmax reduce (both rows, independent chains); tie -> lowest idx.
    #pragma unroll
    for (int off = 32; off > 0; off >>= 1) {
        const float oma = __shfl_xor(ma, off, 64);
        const int   oia = __shfl_xor(ia, off, 64);
        if (oma > ma || (oma == ma && oia < ia)) { ma = oma; ia = oia; }
        const float omb = __shfl_xor(mb, off, 64);
        const int   oib = __shfl_xor(ib, off, 64);
        if (omb > mb || (omb == mb && oib < ib)) { mb = omb; ib = oib; }
    }

    // Sum of exp2(f*log2e + c) for both rows; padding -inf -> 0.
    const float caon = -ma * LOG2E;
    const float cbon = -mb * LOG2E;
    float sa0 = 0.f, sa1 = 0.f, sa2 = 0.f, sa3 = 0.f;
    float sb0 = 0.f, sb1 = 0.f, sb2 = 0.f, sb3 = 0.f;
    #pragma unroll
    for (int k = 0; k < 7; ++k) {
        const float* fa = reinterpret_cast<const float*>(&a[k]);
        const float* fb = reinterpret_cast<const float*>(&b[k]);
        sa0 += exp2f(fmaf(fa[0], LOG2E, caon));
        sa1 += exp2f(fmaf(fa[1], LOG2E, caon));
        sa2 += exp2f(fmaf(fa[2], LOG2E, caon));
        sa3 += exp2f(fmaf(fa[3], LOG2E, caon));
        sb0 += exp2f(fmaf(fb[0], LOG2E, cbon));
        sb1 += exp2f(fmaf(fb[1], LOG2E, cbon));
        sb2 += exp2f(fmaf(fb[2], LOG2E, cbon));
        sb3 += exp2f(fmaf(fb[3], LOG2E, cbon));
    }
    float sa = (sa0 + sa1) + (sa2 + sa3);
    float sb = (sb0 + sb1) + (sb2 + sb3);
    #pragma unroll
    for (int off = 32; off > 0; off >>= 1) {
        sa += __shfl_xor(sa, off, 64);
        sb += __shfl_xor(sb, off, 64);
    }

    __shared__ float part[4];
    if (lane == 0) {
        const float ce0  = logf(sa) + ma - lt0;
        const float pen0 = P[(size_t)tgt0 * NCLS + ia];
        const float ce1  = logf(sb) + mb - lt1;
        const float pen1 = P[(size_t)tgt1 * NCLS + ib];
        part[wave] = (ce0 + pen0) + (ce1 + pen1);
    }
    __syncthreads();
    if (threadIdx.x == 0) {
        ws[blockIdx.x] = (part[0] + part[1]) + (part[2] + part[3]);
    }
}

// Deterministic reduction of 2048 block partials: one float4 per thread.
__global__ __launch_bounds__(512) void cevp_reduce_kernel(
        const float* __restrict__ ws, float* __restrict__ out) {
    __shared__ float sm[8];
    const int tid = threadIdx.x;
    const float4 v = reinterpret_cast<const float4*>(ws)[tid];
    float s = (v.x + v.y) + (v.z + v.w);
    #pragma unroll
    for (int off = 32; off > 0; off >>= 1) {
        s += __shfl_xor(s, off, 64);
    }
    if ((tid & 63) == 0) sm[tid >> 6] = s;
    __syncthreads();
    if (tid < 8) {
        float t = sm[tid];
        #pragma unroll
        for (int off = 4; off > 0; off >>= 1) {
            t += __shfl_xor(t, off, 64);
        }
        if (tid == 0) out[0] = t / (float)NBATCH;
    }
}

extern "C" void kernel_launch(void* const* d_in, const int* in_sizes, int n_in,
                              void* d_out, int out_size, void* d_ws, size_t ws_size,
                              hipStream_t stream) {
    const float* logits  = (const float*)d_in[0];
    const int*   targets = (const int*)d_in[1];
    const float* P       = (const float*)d_in[2];
    float* out = (float*)d_out;
    float* ws  = (float*)d_ws;   // 2048 floats = 8 KB

    cevp_row_kernel<<<NBLOCKS, 256, 0, stream>>>(logits, targets, P, ws);
    cevp_reduce_kernel<<<1, 512, 0, stream>>>(ws, out);
}

// Round 6
// 26.610 us; speedup vs baseline: 1.0457x; 1.0457x over previous
//
#include <hip/hip_runtime.h>
#include <math.h>

#define NCLS 1784
#define NF4 446            // 1784 / 4
#define NBATCH 16384
#define NBLOCKS (NBATCH / 4)   // 4096 row blocks (+1 reducer block)
#define LOG2E 1.4426950408889634f
#define MAGIC 0xC0FFEE42u

// Blocks 0..4095: one wave (64 lanes) per row, 4 rows per block; publish one
// tagged 8-byte partial {MAGIC, value} via relaxed agent-scope atomic store
// (write-through, no fence, no cache maintenance).
// Block 4096: polls the 4096 tags (data-is-the-flag), then reduces all
// partials in fixed index order -> bit-deterministic scalar.
__global__ __launch_bounds__(256) void cevp_fused_kernel(
        const float* __restrict__ logits,
        const int* __restrict__ targets,
        const float* __restrict__ P,
        unsigned long long* __restrict__ slots,
        float* __restrict__ out) {
    const int wave = threadIdx.x >> 6;          // 0..3
    const int lane = threadIdx.x & 63;

    if (blockIdx.x == NBLOCKS) {
        // ---- Reducer block: 256 threads x 16 slots each ----
        const int base = threadIdx.x * 16;
        // Phase A: spin until all 16 tags are MAGIC.
        bool allok = false;
        while (!allok) {
            bool ok = true;
            #pragma unroll
            for (int i = 0; i < 16; ++i) {
                const unsigned long long u = __hip_atomic_load(
                    &slots[base + i], __ATOMIC_RELAXED, __HIP_MEMORY_SCOPE_AGENT);
                ok &= ((unsigned)(u >> 32) == MAGIC);
            }
            allok = ok;
            if (!allok) __builtin_amdgcn_s_sleep(2);
        }
        // Phase B: values are stable now; sum in fixed index order.
        float s = 0.0f;
        #pragma unroll
        for (int i = 0; i < 16; ++i) {
            const unsigned long long u = __hip_atomic_load(
                &slots[base + i], __ATOMIC_RELAXED, __HIP_MEMORY_SCOPE_AGENT);
            s += __uint_as_float((unsigned)u);
        }
        // Deterministic block reduce: wave shuffle then LDS in fixed order.
        #pragma unroll
        for (int off = 32; off > 0; off >>= 1) {
            s += __shfl_xor(s, off, 64);
        }
        __shared__ float sm[4];
        if (lane == 0) sm[wave] = s;
        __syncthreads();
        if (threadIdx.x == 0) {
            out[0] = ((sm[0] + sm[1]) + (sm[2] + sm[3])) / (float)NBATCH;
        }
        return;
    }

    const int row = blockIdx.x * 4 + wave;

    // Hoisted scattered loads: latency overlaps the bulk row loads below.
    const int   tgt = targets[row];
    const float lt  = logits[(size_t)row * NCLS + tgt];

    const float4* __restrict__ rp =
        reinterpret_cast<const float4*>(logits + (size_t)row * NCLS);

    // Whole row into registers: 7 float4 per lane (446 f4 per row).
    float4 v[7];
    #pragma unroll
    for (int k = 0; k < 7; ++k) {
        const int idx = lane + 64 * k;
        if (idx < NF4) {
            v[k] = rp[idx];
        } else {
            v[k] = make_float4(-INFINITY, -INFINITY, -INFINITY, -INFINITY);
        }
    }

    // Per-lane max; compact code = 4k+j (0..27). Ascending scan order ->
    // '>' keeps first occurrence within the lane.
    float m = -INFINITY;
    int code = 0;
    #pragma unroll
    for (int k = 0; k < 7; ++k) {
        const float* f = reinterpret_cast<const float*>(&v[k]);
        #pragma unroll
        for (int j = 0; j < 4; ++j) {
            const bool gt = f[j] > m;
            code = gt ? (k * 4 + j) : code;
            m    = gt ? f[j]        : m;
        }
    }
    // True column index: idx = 256*k + 4*lane + j.
    int mi = ((code >> 2) << 8) + (lane << 2) + (code & 3);

    // Wave-wide argmax reduce; tie -> lowest index (matches jnp.argmax).
    #pragma unroll
    for (int off = 32; off > 0; off >>= 1) {
        const float om = __shfl_xor(m, off, 64);
        const int   oi = __shfl_xor(mi, off, 64);
        if (om > m || (om == m && oi < mi)) { m = om; mi = oi; }
    }

    // Sum of exp2(f*log2e + c); padding lanes hold -inf -> 0.
    const float c = -m * LOG2E;
    float s0 = 0.f, s1 = 0.f, s2 = 0.f, s3 = 0.f;
    #pragma unroll
    for (int k = 0; k < 7; ++k) {
        const float* f = reinterpret_cast<const float*>(&v[k]);
        s0 += exp2f(fmaf(f[0], LOG2E, c));
        s1 += exp2f(fmaf(f[1], LOG2E, c));
        s2 += exp2f(fmaf(f[2], LOG2E, c));
        s3 += exp2f(fmaf(f[3], LOG2E, c));
    }
    float s = (s0 + s1) + (s2 + s3);
    #pragma unroll
    for (int off = 32; off > 0; off >>= 1) {
        s += __shfl_xor(s, off, 64);
    }

    __shared__ float part[4];
    if (lane == 0) {
        const float ce  = logf(s) + m - lt;            // -log_softmax at target
        const float pen = P[(size_t)tgt * NCLS + mi];  // penalty[target, argmax]
        part[wave] = ce + pen;
    }
    __syncthreads();
    if (threadIdx.x == 0) {
        const float partial = (part[0] + part[1]) + (part[2] + part[3]);
        const unsigned long long u =
            ((unsigned long long)MAGIC << 32) |
            (unsigned long long)__float_as_uint(partial);
        // Relaxed agent-scope 8B atomic store: write-through to the coherence
        // point. No release fence -> no L2 writeback storm (round-3 lesson).
        __hip_atomic_store(&slots[blockIdx.x], u, __ATOMIC_RELAXED,
                           __HIP_MEMORY_SCOPE_AGENT);
    }
}

extern "C" void kernel_launch(void* const* d_in, const int* in_sizes, int n_in,
                              void* d_out, int out_size, void* d_ws, size_t ws_size,
                              hipStream_t stream) {
    const float* logits  = (const float*)d_in[0];
    const int*   targets = (const int*)d_in[1];
    const float* P       = (const float*)d_in[2];
    float* out = (float*)d_out;
    unsigned long long* slots = (unsigned long long*)d_ws;   // 4096 * 8 = 32 KB

    cevp_fused_kernel<<<NBLOCKS + 1, 256, 0, stream>>>(logits, targets, P, slots, out);
}

// Round 7
// 26.465 us; speedup vs baseline: 1.0515x; 1.0055x over previous
//
#include <hip/hip_runtime.h>
#include <math.h>

#define NCLS 1784
#define NF4 446            // 1784 / 4
#define NBATCH 16384
#define NBLOCKS (NBATCH / 4)   // 4096
#define LOG2E 1.4426950408889634f

// One wave (64 lanes) per row; 4 rows per 256-thread block.
// The 28 row values per lane are PINNED into VGPRs via empty asm so the
// compiler cannot rematerialize them with a second memory pass (round-6
// diagnosis: VGPR_Count=24 proved it was re-loading the row for the exp
// pass instead of keeping it register-resident).
__global__ __launch_bounds__(256) void cevp_row_kernel(
        const float* __restrict__ logits,
        const int* __restrict__ targets,
        const float* __restrict__ P,
        float* __restrict__ ws) {
    const int wave = threadIdx.x >> 6;          // 0..3
    const int lane = threadIdx.x & 63;
    const int row  = blockIdx.x * 4 + wave;

    // Hoisted scattered loads: latency overlaps the bulk row loads below.
    const int   tgt = targets[row];
    const float lt  = logits[(size_t)row * NCLS + tgt];

    const float4* __restrict__ rp =
        reinterpret_cast<const float4*>(logits + (size_t)row * NCLS);

    // Whole row into 28 named registers: 7 float4 loads per lane.
    float x[28];
    #pragma unroll
    for (int k = 0; k < 7; ++k) {
        const int idx = lane + 64 * k;
        float4 t;
        if (idx < NF4) {
            t = rp[idx];
        } else {
            t = make_float4(-INFINITY, -INFINITY, -INFINITY, -INFINITY);
        }
        x[4 * k + 0] = t.x;
        x[4 * k + 1] = t.y;
        x[4 * k + 2] = t.z;
        x[4 * k + 3] = t.w;
    }
    // Pin: force each value to live in a VGPR from here on. The asm's
    // "output" cannot be recomputed from memory, so no re-load pass.
    #pragma unroll
    for (int i = 0; i < 28; ++i) {
        asm volatile("" : "+v"(x[i]));
    }

    // Per-lane max; compact code 0..27. Ascending scan -> '>' keeps the
    // first occurrence within the lane.
    float m = -INFINITY;
    int code = 0;
    #pragma unroll
    for (int i = 0; i < 28; ++i) {
        const bool gt = x[i] > m;
        code = gt ? i    : code;
        m    = gt ? x[i] : m;
    }
    // True column index: idx = 256*(i>>2) + 4*lane + (i&3).
    int mi = ((code >> 2) << 8) + (lane << 2) + (code & 3);

    // Wave-wide argmax reduce; tie -> lowest index (matches jnp.argmax).
    #pragma unroll
    for (int off = 32; off > 0; off >>= 1) {
        const float om = __shfl_xor(m, off, 64);
        const int   oi = __shfl_xor(mi, off, 64);
        if (om > m || (om == m && oi < mi)) { m = om; mi = oi; }
    }

    // Sum of exp2(x*log2e + c) over the register-resident row.
    const float c = -m * LOG2E;
    float s0 = 0.f, s1 = 0.f, s2 = 0.f, s3 = 0.f;
    #pragma unroll
    for (int k = 0; k < 7; ++k) {
        s0 += exp2f(fmaf(x[4 * k + 0], LOG2E, c));
        s1 += exp2f(fmaf(x[4 * k + 1], LOG2E, c));
        s2 += exp2f(fmaf(x[4 * k + 2], LOG2E, c));
        s3 += exp2f(fmaf(x[4 * k + 3], LOG2E, c));
    }
    float s = (s0 + s1) + (s2 + s3);
    #pragma unroll
    for (int off = 32; off > 0; off >>= 1) {
        s += __shfl_xor(s, off, 64);
    }

    __shared__ float part[4];
    if (lane == 0) {
        const float ce  = logf(s) + m - lt;            // -log_softmax at target
        const float pen = P[(size_t)tgt * NCLS + mi];  // penalty[target, argmax]
        part[wave] = ce + pen;
    }
    __syncthreads();
    if (threadIdx.x == 0) {
        ws[blockIdx.x] = (part[0] + part[1]) + (part[2] + part[3]);
    }
}

// Deterministic reduction of 4096 block partials: one float4 per thread.
__global__ __launch_bounds__(1024) void cevp_reduce_kernel(
        const float* __restrict__ ws, float* __restrict__ out) {
    __shared__ float sm[16];
    const int tid = threadIdx.x;
    const float4 v = reinterpret_cast<const float4*>(ws)[tid];
    float s = (v.x + v.y) + (v.z + v.w);
    #pragma unroll
    for (int off = 32; off > 0; off >>= 1) {
        s += __shfl_xor(s, off, 64);
    }
    if ((tid & 63) == 0) sm[tid >> 6] = s;
    __syncthreads();
    if (tid < 16) {
        float t = sm[tid];
        #pragma unroll
        for (int off = 8; off > 0; off >>= 1) {
            t += __shfl_xor(t, off, 64);
        }
        if (tid == 0) out[0] = t / (float)NBATCH;
    }
}

extern "C" void kernel_launch(void* const* d_in, const int* in_sizes, int n_in,
                              void* d_out, int out_size, void* d_ws, size_t ws_size,
                              hipStream_t stream) {
    const float* logits  = (const float*)d_in[0];
    const int*   targets = (const int*)d_in[1];
    const float* P       = (const float*)d_in[2];
    float* out = (float*)d_out;
    float* ws  = (float*)d_ws;   // 4096 floats = 16 KB

    cevp_row_kernel<<<NBLOCKS, 256, 0, stream>>>(logits, targets, P, ws);
    cevp_reduce_kernel<<<1, 1024, 0, stream>>>(ws, out);
}